// Round 3
// baseline (1110.444 us; speedup 1.0000x reference)
//
#include <hip/hip_runtime.h>

#define N_USERS 50000
#define N_ITEMS 50000
#define FEAT    128
#define NEDGE   600000
#define BLK_PER_HALF 782   // ceil(50000/64)

// ---------- edge dtype handling (harness may upload int64 or int32) ----------
__global__ void detect_i64(const unsigned int* __restrict__ e, int* __restrict__ flag) {
  unsigned int hi = e[2 * threadIdx.x + 1];
  unsigned long long any = __ballot(hi != 0u);
  if (threadIdx.x == 0) flag[0] = (any == 0ull) ? 1 : 0;
}

__device__ __forceinline__ int edge_at(const void* __restrict__ edges, long i, int is64) {
  return is64 ? (int)((const long long*)edges)[i] : ((const int*)edges)[i];
}

__global__ __launch_bounds__(256) void deg_kernel(
    const void* __restrict__ ef, const void* __restrict__ eb, const void* __restrict__ ebb,
    float* __restrict__ degF, float* __restrict__ degB, float* __restrict__ degBB,
    const int* __restrict__ flag) {
  int i = blockIdx.x * blockDim.x + threadIdx.x;
  int is64 = *flag;
  if (i < NEDGE) {
    unsafeAtomicAdd(&degF[edge_at(ef, NEDGE + i, is64)], 1.0f);
    unsafeAtomicAdd(&degB[edge_at(eb, NEDGE + i, is64)], 1.0f);
    unsafeAtomicAdd(&degBB[edge_at(ebb, NEDGE + i, is64)], 1.0f);
  }
}

// one 64-lane wave per edge; each lane handles 2 of the 128 features
__global__ __launch_bounds__(256) void scatter_kernel(
    const float* __restrict__ x, const void* __restrict__ edges, float* __restrict__ agg,
    const int* __restrict__ flag) {
  long gid = (long)blockIdx.x * blockDim.x + threadIdx.x;
  int e = (int)(gid >> 6);
  int lane = (int)(gid & 63);
  if (e >= NEDGE) return;
  int is64 = *flag;
  int src = edge_at(edges, e, is64);          // edges[0][e]
  int dst = edge_at(edges, NEDGE + e, is64);  // edges[1][e]
  const float* xs = x + (long)src * FEAT;
  float* ag = agg + (long)dst * FEAT;
  unsafeAtomicAdd(&ag[lane],      xs[lane]);
  unsafeAtomicAdd(&ag[lane + 64], xs[lane + 64]);
}

// Single kernel computing BOTH output halves.
// block b < 782: user rows; b >= 782: item rows. 64 rows x 128 cols per block.
__global__ __launch_bounds__(256) void fused_gemm_all(
    const float* __restrict__ aggF, const float* __restrict__ aggBB,
    const float* __restrict__ aggB,
    const float* __restrict__ degF, const float* __restrict__ degBB,
    const float* __restrict__ degB,
    const float* __restrict__ x_user, const float* __restrict__ x_item,
    const float* __restrict__ W_fol, const float* __restrict__ W_bb,
    const float* __restrict__ W_buy, const float* __restrict__ W_lu,
    const float* __restrict__ W_li,
    const float* __restrict__ b_lu, const float* __restrict__ b_li,
    float* __restrict__ out) {
  __shared__ float As[64][132];   // 64 rows x full K=128 (stride 132: 2-way bank alias, free)
  __shared__ float Ws[32][128];   // one K-chunk of W
  const int t = threadIdx.x;
  const int b = blockIdx.x;
  const int half = (b >= BLK_PER_HALF) ? 1 : 0;
  const int g0 = (half ? b - BLK_PER_HALF : b) * 64;
  const int nsrc = half ? 2 : 3;
  const float* __restrict__ bias = half ? b_li : b_lu;

  const int tn = t & 15;
  const int tm = t >> 4;
  const int tn8 = tn * 8;
  const int tm4 = tm * 4;

  float acc[4][8] = {};

  for (int s = 0; s < nsrc; ++s) {
    const float* Ap; const float* dgp; const float* Wp;
    if (half == 0) {
      Ap  = (s == 0) ? aggF  : (s == 1) ? aggBB : x_user;
      dgp = (s == 0) ? degF  : (s == 1) ? degBB : nullptr;
      Wp  = (s == 0) ? W_fol : (s == 1) ? W_bb  : W_lu;
    } else {
      Ap  = (s == 0) ? aggB  : x_item;
      dgp = (s == 0) ? degB  : nullptr;
      Wp  = (s == 0) ? W_buy : W_li;
    }

    // stage A tile (64 x 128), deg-normalized on the fly
#pragma unroll
    for (int i = 0; i < 8; ++i) {
      int idx = t + i * 256;        // float4 slot, 0..2047
      int row = idx >> 5;           // 32 float4s per row
      int c4 = (idx & 31) << 2;
      int gr = g0 + row;
      float4 v = make_float4(0.f, 0.f, 0.f, 0.f);
      float rd = 1.0f;
      if (gr < N_USERS) {           // both halves have 50000 rows
        v = *reinterpret_cast<const float4*>(Ap + (long)gr * FEAT + c4);
        if (dgp) rd = 1.0f / fmaxf(dgp[gr], 1.0f);
      }
      As[row][c4 + 0] = v.x * rd;
      As[row][c4 + 1] = v.y * rd;
      As[row][c4 + 2] = v.z * rd;
      As[row][c4 + 3] = v.w * rd;
    }

    for (int k0 = 0; k0 < FEAT; k0 += 32) {
      // stage W chunk (rows k0..k0+31, all 128 cols)
#pragma unroll
      for (int i = 0; i < 4; ++i) {
        int idx = t + i * 256;      // float4 slot, 0..1023
        int row = idx >> 5;
        int c4 = (idx & 31) << 2;
        *reinterpret_cast<float4*>(&Ws[row][c4]) =
            *reinterpret_cast<const float4*>(Wp + (long)(k0 + row) * FEAT + c4);
      }
      __syncthreads();
#pragma unroll
      for (int kk = 0; kk < 32; ++kk) {
        float a[4];
        a[0] = As[tm4 + 0][k0 + kk];   // <-- fixed: k0 + kk (was kk)
        a[1] = As[tm4 + 1][k0 + kk];
        a[2] = As[tm4 + 2][k0 + kk];
        a[3] = As[tm4 + 3][k0 + kk];
        float4 w0 = *reinterpret_cast<const float4*>(&Ws[kk][tn8]);
        float4 w1 = *reinterpret_cast<const float4*>(&Ws[kk][tn8 + 4]);
        float w[8] = {w0.x, w0.y, w0.z, w0.w, w1.x, w1.y, w1.z, w1.w};
#pragma unroll
        for (int r = 0; r < 4; ++r)
#pragma unroll
          for (int c = 0; c < 8; ++c) acc[r][c] = fmaf(a[r], w[c], acc[r][c]);
      }
      __syncthreads();
    }
  }

  // epilogue: bias + relu, store
  float4 b0 = *reinterpret_cast<const float4*>(bias + tn8);
  float4 b1 = *reinterpret_cast<const float4*>(bias + tn8 + 4);
  float bb[8] = {b0.x, b0.y, b0.z, b0.w, b1.x, b1.y, b1.z, b1.w};
#pragma unroll
  for (int r = 0; r < 4; ++r) {
    int gr = g0 + tm4 + r;
    if (gr < N_USERS) {
      long orow = (long)(half ? N_USERS : 0) + gr;
      float o[8];
#pragma unroll
      for (int c = 0; c < 8; ++c) o[c] = fmaxf(acc[r][c] + bb[c], 0.0f);
      *reinterpret_cast<float4*>(out + orow * FEAT + tn8) =
          make_float4(o[0], o[1], o[2], o[3]);
      *reinterpret_cast<float4*>(out + orow * FEAT + tn8 + 4) =
          make_float4(o[4], o[5], o[6], o[7]);
    }
  }
}

extern "C" void kernel_launch(void* const* d_in, const int* in_sizes, int n_in,
                              void* d_out, int out_size, void* d_ws, size_t ws_size,
                              hipStream_t stream) {
  const float* x_user = (const float*)d_in[0];
  const float* x_item = (const float*)d_in[1];
  const void* e_fol = d_in[2];    // follows: user -> user
  const void* e_buy = d_in[3];    // buys: user -> item
  const void* e_bb  = d_in[4];    // bought_by: item -> user
  const float* W_fol = (const float*)d_in[5];
  const float* W_buy = (const float*)d_in[6];
  const float* W_bb  = (const float*)d_in[7];
  const float* W_lu  = (const float*)d_in[8];
  const float* b_lu  = (const float*)d_in[9];
  const float* W_li  = (const float*)d_in[10];
  const float* b_li  = (const float*)d_in[11];
  float* out = (float*)d_out;

  float* ws = (float*)d_ws;
  float* aggF  = ws;                 // 50000*128
  float* aggBB = ws + 6400000;       // 50000*128
  float* aggB  = ws + 12800000;      // 50000*128
  float* degF  = ws + 19200000;      // 50000
  float* degBB = ws + 19250000;      // 50000
  float* degB  = ws + 19300000;      // 50000
  int*   flag  = (int*)(ws + 19350000);

  // zero agg + deg (ws is poisoned 0xAA before every call)
  hipMemsetAsync(d_ws, 0, 19350000ull * sizeof(float), stream);

  detect_i64<<<1, 64, 0, stream>>>((const unsigned int*)e_fol, flag);

  deg_kernel<<<(NEDGE + 255) / 256, 256, 0, stream>>>(e_fol, e_buy, e_bb,
                                                      degF, degB, degBB, flag);

  const int sblocks = (NEDGE * 64 + 255) / 256;  // 150000 blocks, 4 edges/block
  scatter_kernel<<<sblocks, 256, 0, stream>>>(x_user, e_fol, aggF, flag);
  scatter_kernel<<<sblocks, 256, 0, stream>>>(x_item, e_bb,  aggBB, flag);
  scatter_kernel<<<sblocks, 256, 0, stream>>>(x_user, e_buy, aggB, flag);

  fused_gemm_all<<<2 * BLK_PER_HALF, 256, 0, stream>>>(
      aggF, aggBB, aggB, degF, degBB, degB, x_user, x_item,
      W_fol, W_bb, W_buy, W_lu, W_li, b_lu, b_li, out);
}

// Round 4
// 599.928 us; speedup vs baseline: 1.8510x; 1.8510x over previous
//
#include <hip/hip_runtime.h>

#define N_NODES 50000   // both ntypes have 50000 rows
#define FEAT    128
#define NEDGE   600000
#define BLK_PER_HALF 782   // ceil(50000/64)
#define SCAN_BLKS 196      // ceil(50000/256)

// ---------- edge dtype handling (harness may upload int64 or int32) ----------
__global__ void detect_i64(const unsigned int* __restrict__ e, int* __restrict__ flag) {
  unsigned int hi = e[2 * threadIdx.x + 1];
  unsigned long long any = __ballot(hi != 0u);
  if (threadIdx.x == 0) flag[0] = (any == 0ull) ? 1 : 0;
}

__device__ __forceinline__ int edge_at(const void* __restrict__ edges, long i, int is64) {
  return is64 ? (int)((const long long*)edges)[i] : ((const int*)edges)[i];
}

// ---------- CSR build ----------
// rel0: follows (e_fol, dst=user), rel1: bought_by (e_bb, dst=user), rel2: buys (e_buy, dst=item)
__global__ __launch_bounds__(256) void hist_kernel(
    const void* __restrict__ e0, const void* __restrict__ e1, const void* __restrict__ e2,
    int* __restrict__ rp0, int* __restrict__ rp1, int* __restrict__ rp2,
    const int* __restrict__ flag) {
  int i = blockIdx.x * blockDim.x + threadIdx.x;
  int is64 = *flag;
  if (i < NEDGE) {
    atomicAdd(&rp0[1 + edge_at(e0, NEDGE + i, is64)], 1);
    atomicAdd(&rp1[1 + edge_at(e1, NEDGE + i, is64)], 1);
    atomicAdd(&rp2[1 + edge_at(e2, NEDGE + i, is64)], 1);
  }
}

// 256-thread block inclusive scan (wave shuffles + 4-entry LDS)
__device__ __forceinline__ int block_scan_incl(int v, int* wsum) {
  int lane = threadIdx.x & 63, wid = threadIdx.x >> 6;
#pragma unroll
  for (int d = 1; d < 64; d <<= 1) {
    int n = __shfl_up(v, d, 64);
    if (lane >= d) v += n;
  }
  if (lane == 63) wsum[wid] = v;
  __syncthreads();
  if (threadIdx.x < 4) {
    int s = wsum[threadIdx.x];
#pragma unroll
    for (int d = 1; d < 4; d <<= 1) {
      int n = __shfl_up(s, d, 64);
      if ((int)threadIdx.x >= d) s += n;
    }
    wsum[threadIdx.x] = s;
  }
  __syncthreads();
  return v + (wid ? wsum[wid - 1] : 0);
}

// scan counts within 256-element chunks; write inclusive to rp[1+i], exclusive to cur[i]
__global__ __launch_bounds__(256) void scan_a(
    int* __restrict__ rp0, int* __restrict__ rp1, int* __restrict__ rp2,
    int* __restrict__ cur0, int* __restrict__ cur1, int* __restrict__ cur2,
    int* __restrict__ bsums) {
  __shared__ int wsum[4];
  int rel = blockIdx.x / SCAN_BLKS;
  int blk = blockIdx.x % SCAN_BLKS;
  int* rp  = (rel == 0) ? rp0  : (rel == 1) ? rp1  : rp2;
  int* cur = (rel == 0) ? cur0 : (rel == 1) ? cur1 : cur2;
  int idx = blk * 256 + threadIdx.x;
  int c = (idx < N_NODES) ? rp[1 + idx] : 0;
  int incl = block_scan_incl(c, wsum);
  if (idx < N_NODES) {
    rp[1 + idx] = incl;
    cur[idx] = incl - c;   // exclusive = row start (pre-offset)
  }
  if (threadIdx.x == 255) bsums[rel * 256 + blk] = incl;  // block total
}

// exclusive-scan the per-block totals (one block per relation)
__global__ __launch_bounds__(256) void scan_b(int* __restrict__ bsums) {
  __shared__ int wsum[4];
  int rel = blockIdx.x;
  int t = threadIdx.x;
  int own = (t < SCAN_BLKS) ? bsums[rel * 256 + t] : 0;
  int incl = block_scan_incl(own, wsum);
  if (t < SCAN_BLKS) bsums[rel * 256 + t] = incl - own;  // exclusive
}

__global__ __launch_bounds__(256) void scan_c(
    int* __restrict__ rp0, int* __restrict__ rp1, int* __restrict__ rp2,
    int* __restrict__ cur0, int* __restrict__ cur1, int* __restrict__ cur2,
    const int* __restrict__ bsums) {
  int rel = blockIdx.x / SCAN_BLKS;
  int blk = blockIdx.x % SCAN_BLKS;
  int* rp  = (rel == 0) ? rp0  : (rel == 1) ? rp1  : rp2;
  int* cur = (rel == 0) ? cur0 : (rel == 1) ? cur1 : cur2;
  int off = bsums[rel * 256 + blk];
  int idx = blk * 256 + threadIdx.x;
  if (idx < N_NODES) {
    rp[1 + idx] += off;
    cur[idx] += off;
  }
}

__global__ __launch_bounds__(256) void fill_kernel(
    const void* __restrict__ e0, const void* __restrict__ e1, const void* __restrict__ e2,
    int* __restrict__ cur0, int* __restrict__ cur1, int* __restrict__ cur2,
    int* __restrict__ csr0, int* __restrict__ csr1, int* __restrict__ csr2,
    const int* __restrict__ flag) {
  int i = blockIdx.x * blockDim.x + threadIdx.x;
  int is64 = *flag;
  if (i < NEDGE) {
    int s0 = edge_at(e0, i, is64), d0 = edge_at(e0, NEDGE + i, is64);
    csr0[atomicAdd(&cur0[d0], 1)] = s0;
    int s1 = edge_at(e1, i, is64), d1 = edge_at(e1, NEDGE + i, is64);
    csr1[atomicAdd(&cur1[d1], 1)] = s1;
    int s2 = edge_at(e2, i, is64), d2 = edge_at(e2, NEDGE + i, is64);
    csr2[atomicAdd(&cur2[d2], 1)] = s2;
  }
}

// ---------- gather aggregation: one wave per dst row ----------
__global__ __launch_bounds__(256) void agg_kernel(
    const float* __restrict__ x, const int* __restrict__ rp,
    const int* __restrict__ csr, float* __restrict__ agg) {
  int w = (blockIdx.x * 256 + threadIdx.x) >> 6;
  int lane = threadIdx.x & 63;
  if (w >= N_NODES) return;
  const float2* __restrict__ xv = (const float2*)x;
  int beg = rp[w], end = rp[w + 1];
  float2 acc = make_float2(0.f, 0.f);
  int e = beg;
  for (; e + 3 < end; e += 4) {
    int s0 = csr[e], s1 = csr[e + 1], s2 = csr[e + 2], s3 = csr[e + 3];
    float2 v0 = xv[(long)s0 * 64 + lane];
    float2 v1 = xv[(long)s1 * 64 + lane];
    float2 v2 = xv[(long)s2 * 64 + lane];
    float2 v3 = xv[(long)s3 * 64 + lane];
    acc.x += v0.x + v1.x + v2.x + v3.x;
    acc.y += v0.y + v1.y + v2.y + v3.y;
  }
  for (; e < end; ++e) {
    int s = csr[e];
    float2 v = xv[(long)s * 64 + lane];
    acc.x += v.x; acc.y += v.y;
  }
  ((float2*)agg)[(long)w * 64 + lane] = acc;
}

// ---------- fused GEMM (both halves; deg from row_ptr) ----------
__global__ __launch_bounds__(256) void fused_gemm_all(
    const float* __restrict__ aggF, const float* __restrict__ aggBB,
    const float* __restrict__ aggB,
    const int* __restrict__ rp0, const int* __restrict__ rp1, const int* __restrict__ rp2,
    const float* __restrict__ x_user, const float* __restrict__ x_item,
    const float* __restrict__ W_fol, const float* __restrict__ W_bb,
    const float* __restrict__ W_buy, const float* __restrict__ W_lu,
    const float* __restrict__ W_li,
    const float* __restrict__ b_lu, const float* __restrict__ b_li,
    float* __restrict__ out, int blk_off) {
  __shared__ float As[64][132];
  __shared__ float Ws[32][128];
  const int t = threadIdx.x;
  const int b = blockIdx.x + blk_off;
  const int half = (b >= BLK_PER_HALF) ? 1 : 0;
  const int g0 = (half ? b - BLK_PER_HALF : b) * 64;
  const int nsrc = half ? 2 : 3;
  const float* __restrict__ bias = half ? b_li : b_lu;

  const int tn = t & 15;
  const int tm = t >> 4;
  const int tn8 = tn * 8;
  const int tm4 = tm * 4;

  float acc[4][8] = {};

  for (int s = 0; s < nsrc; ++s) {
    const float* Ap; const int* rpp; const float* Wp;
    if (half == 0) {
      Ap  = (s == 0) ? aggF  : (s == 1) ? aggBB : x_user;
      rpp = (s == 0) ? rp0   : (s == 1) ? rp1   : nullptr;
      Wp  = (s == 0) ? W_fol : (s == 1) ? W_bb  : W_lu;
    } else {
      Ap  = (s == 0) ? aggB  : x_item;
      rpp = (s == 0) ? rp2   : nullptr;
      Wp  = (s == 0) ? W_buy : W_li;
    }

#pragma unroll
    for (int i = 0; i < 8; ++i) {
      int idx = t + i * 256;
      int row = idx >> 5;
      int c4 = (idx & 31) << 2;
      int gr = g0 + row;
      float4 v = make_float4(0.f, 0.f, 0.f, 0.f);
      float rd = 1.0f;
      if (gr < N_NODES) {
        v = *reinterpret_cast<const float4*>(Ap + (long)gr * FEAT + c4);
        if (rpp) rd = 1.0f / fmaxf((float)(rpp[gr + 1] - rpp[gr]), 1.0f);
      }
      As[row][c4 + 0] = v.x * rd;
      As[row][c4 + 1] = v.y * rd;
      As[row][c4 + 2] = v.z * rd;
      As[row][c4 + 3] = v.w * rd;
    }

    for (int k0 = 0; k0 < FEAT; k0 += 32) {
#pragma unroll
      for (int i = 0; i < 4; ++i) {
        int idx = t + i * 256;
        int row = idx >> 5;
        int c4 = (idx & 31) << 2;
        *reinterpret_cast<float4*>(&Ws[row][c4]) =
            *reinterpret_cast<const float4*>(Wp + (long)(k0 + row) * FEAT + c4);
      }
      __syncthreads();
#pragma unroll
      for (int kk = 0; kk < 32; ++kk) {
        float a[4];
        a[0] = As[tm4 + 0][k0 + kk];
        a[1] = As[tm4 + 1][k0 + kk];
        a[2] = As[tm4 + 2][k0 + kk];
        a[3] = As[tm4 + 3][k0 + kk];
        float4 w0 = *reinterpret_cast<const float4*>(&Ws[kk][tn8]);
        float4 w1 = *reinterpret_cast<const float4*>(&Ws[kk][tn8 + 4]);
        float w[8] = {w0.x, w0.y, w0.z, w0.w, w1.x, w1.y, w1.z, w1.w};
#pragma unroll
        for (int r = 0; r < 4; ++r)
#pragma unroll
          for (int c = 0; c < 8; ++c) acc[r][c] = fmaf(a[r], w[c], acc[r][c]);
      }
      __syncthreads();
    }
  }

  float4 bv0 = *reinterpret_cast<const float4*>(bias + tn8);
  float4 bv1 = *reinterpret_cast<const float4*>(bias + tn8 + 4);
  float bb[8] = {bv0.x, bv0.y, bv0.z, bv0.w, bv1.x, bv1.y, bv1.z, bv1.w};
#pragma unroll
  for (int r = 0; r < 4; ++r) {
    int gr = g0 + tm4 + r;
    if (gr < N_NODES) {
      long orow = (long)(half ? N_NODES : 0) + gr;
      float o[8];
#pragma unroll
      for (int c = 0; c < 8; ++c) o[c] = fmaxf(acc[r][c] + bb[c], 0.0f);
      *reinterpret_cast<float4*>(out + orow * FEAT + tn8) =
          make_float4(o[0], o[1], o[2], o[3]);
      *reinterpret_cast<float4*>(out + orow * FEAT + tn8 + 4) =
          make_float4(o[4], o[5], o[6], o[7]);
    }
  }
}

extern "C" void kernel_launch(void* const* d_in, const int* in_sizes, int n_in,
                              void* d_out, int out_size, void* d_ws, size_t ws_size,
                              hipStream_t stream) {
  const float* x_user = (const float*)d_in[0];
  const float* x_item = (const float*)d_in[1];
  const void* e_fol = d_in[2];
  const void* e_buy = d_in[3];
  const void* e_bb  = d_in[4];
  const float* W_fol = (const float*)d_in[5];
  const float* W_buy = (const float*)d_in[6];
  const float* W_bb  = (const float*)d_in[7];
  const float* W_lu  = (const float*)d_in[8];
  const float* b_lu  = (const float*)d_in[9];
  const float* W_li  = (const float*)d_in[10];
  const float* b_li  = (const float*)d_in[11];
  float* out = (float*)d_out;

  // ws layout (4B units): [aggF][aggBB][aggB?][csr0..2][rp0..2][cur0..2][bsums][flag]
  const size_t INT_CNT = 2100817;
  bool big = ws_size >= (size_t)(19200000 + INT_CNT) * 4;
  float* ws = (float*)d_ws;
  float* aggF  = ws;
  float* aggBB = ws + 6400000;
  float* aggB  = big ? (ws + 12800000) : ws;   // small path: reuse aggF slot for rel2
  long intBase = big ? 19200000 : 12800000;
  int* ip   = (int*)d_ws + intBase;
  int* csr0 = ip;
  int* csr1 = ip + 600000;
  int* csr2 = ip + 1200000;
  int* rp0  = ip + 1800000;            // 50016 each (50001 used)
  int* rp1  = rp0 + 50016;
  int* rp2  = rp1 + 50016;
  int* cur0 = ip + 1950048;            // 50000 each
  int* cur1 = cur0 + 50000;
  int* cur2 = cur1 + 50000;
  int* bsums = ip + 2100048;           // 3 x 256
  int* flag  = ip + 2100816;

  // zero only the rp count region (agg arrays are fully overwritten)
  hipMemsetAsync(rp0, 0, 150048ull * sizeof(int), stream);

  detect_i64<<<1, 64, 0, stream>>>((const unsigned int*)e_fol, flag);

  const int eblocks = (NEDGE + 255) / 256;
  hist_kernel<<<eblocks, 256, 0, stream>>>(e_fol, e_bb, e_buy, rp0, rp1, rp2, flag);
  scan_a<<<3 * SCAN_BLKS, 256, 0, stream>>>(rp0, rp1, rp2, cur0, cur1, cur2, bsums);
  scan_b<<<3, 256, 0, stream>>>(bsums);
  scan_c<<<3 * SCAN_BLKS, 256, 0, stream>>>(rp0, rp1, rp2, cur0, cur1, cur2, bsums);
  fill_kernel<<<eblocks, 256, 0, stream>>>(e_fol, e_bb, e_buy, cur0, cur1, cur2,
                                           csr0, csr1, csr2, flag);

  const int ablocks = N_NODES / 4;  // 12500 blocks x 4 waves
  agg_kernel<<<ablocks, 256, 0, stream>>>(x_user, rp0, csr0, aggF);
  agg_kernel<<<ablocks, 256, 0, stream>>>(x_item, rp1, csr1, aggBB);

  if (big) {
    agg_kernel<<<ablocks, 256, 0, stream>>>(x_user, rp2, csr2, aggB);
    fused_gemm_all<<<2 * BLK_PER_HALF, 256, 0, stream>>>(
        aggF, aggBB, aggB, rp0, rp1, rp2, x_user, x_item,
        W_fol, W_bb, W_buy, W_lu, W_li, b_lu, b_li, out, 0);
  } else {
    // user half first (reads aggF, aggBB), then rel2 agg reuses aggF's space
    fused_gemm_all<<<BLK_PER_HALF, 256, 0, stream>>>(
        aggF, aggBB, aggB, rp0, rp1, rp2, x_user, x_item,
        W_fol, W_bb, W_buy, W_lu, W_li, b_lu, b_li, out, 0);
    agg_kernel<<<ablocks, 256, 0, stream>>>(x_user, rp2, csr2, aggB);
    fused_gemm_all<<<BLK_PER_HALF, 256, 0, stream>>>(
        aggF, aggBB, aggB, rp0, rp1, rp2, x_user, x_item,
        W_fol, W_bb, W_buy, W_lu, W_li, b_lu, b_li, out, BLK_PER_HALF);
  }
}

// Round 5
// 453.877 us; speedup vs baseline: 2.4466x; 1.3218x over previous
//
#include <hip/hip_runtime.h>

#define N_NODES 50000
#define FEAT    128
#define NEDGE   600000
#define BLK_PER_HALF 782   // ceil(50000/64)
#define SCAN_BLKS 196      // ceil(50000/256)

#define NB_HIST 2344       // ceil(600000/256)
#define NB_CVT  6250       // 2 x 3125 (each x: 6.4M floats / (256*8))
#define NB_W    5

typedef __attribute__((ext_vector_type(8))) short short8;
typedef __attribute__((ext_vector_type(4))) float f32x4;

// ---------- bf16 helpers ----------
__device__ __forceinline__ unsigned short f2bf(float f) {
  unsigned u = __float_as_uint(f);
  return (unsigned short)((u + 0x7fffu + ((u >> 16) & 1u)) >> 16);
}
__device__ __forceinline__ float bflo(unsigned u) { return __uint_as_float(u << 16); }
__device__ __forceinline__ float bfhi(unsigned u) { return __uint_as_float(u & 0xffff0000u); }

// ---------- edge dtype handling ----------
__global__ void detect_i64(const unsigned int* __restrict__ e, int* __restrict__ flag) {
  unsigned int hi = e[2 * threadIdx.x + 1];
  unsigned long long any = __ballot(hi != 0u);
  if (threadIdx.x == 0) flag[0] = (any == 0ull) ? 1 : 0;
}
__device__ __forceinline__ int edge_at(const void* __restrict__ edges, long i, int is64) {
  return is64 ? (int)((const long long*)edges)[i] : ((const int*)edges)[i];
}

// ---------- fused: dst histogram + x->bf16 conversion + W fragment pack ----------
__global__ __launch_bounds__(256) void hist_cvt(
    const void* __restrict__ e0, const void* __restrict__ e1, const void* __restrict__ e2,
    int* __restrict__ rp0, int* __restrict__ rp1, int* __restrict__ rp2,
    const float* __restrict__ xu, const float* __restrict__ xi,
    const float* __restrict__ W_fol, const float* __restrict__ W_bb,
    const float* __restrict__ W_lu, const float* __restrict__ W_buy,
    const float* __restrict__ W_li,
    unsigned short* __restrict__ xu_b, unsigned short* __restrict__ xi_b,
    unsigned short* __restrict__ wfrag, const int* __restrict__ flag) {
  int b = blockIdx.x;
  if (b < NB_HIST) {
    int i = b * 256 + threadIdx.x;
    int is64 = *flag;
    if (i < NEDGE) {
      atomicAdd(&rp0[1 + edge_at(e0, NEDGE + i, is64)], 1);
      atomicAdd(&rp1[1 + edge_at(e1, NEDGE + i, is64)], 1);
      atomicAdd(&rp2[1 + edge_at(e2, NEDGE + i, is64)], 1);
    }
  } else if (b < NB_HIST + NB_CVT) {
    int cb = b - NB_HIST;
    const float* src = (cb < 3125) ? xu : xi;
    unsigned short* dst = (cb < 3125) ? xu_b : xi_b;
    int lb = (cb < 3125) ? cb : cb - 3125;
    size_t base = ((size_t)lb * 256 + threadIdx.x) * 8;   // 8 floats/thread
    float4 v0 = *reinterpret_cast<const float4*>(src + base);
    float4 v1 = *reinterpret_cast<const float4*>(src + base + 4);
    uint4 o;
    o.x = f2bf(v0.x) | ((unsigned)f2bf(v0.y) << 16);
    o.y = f2bf(v0.z) | ((unsigned)f2bf(v0.w) << 16);
    o.z = f2bf(v1.x) | ((unsigned)f2bf(v1.y) << 16);
    o.w = f2bf(v1.z) | ((unsigned)f2bf(v1.w) << 16);
    *reinterpret_cast<uint4*>(dst + base) = o;
  } else {
    // pack W[s] (128x128 f32, [k][n]) into per-lane B-fragment order:
    // wfrag[((s*4+kc)*8+nt)*64 + q*16+nl][j] = W[kc*32+q*8+j][nt*16+nl]
    int s = b - (NB_HIST + NB_CVT);
    const float* W = (s == 0) ? W_fol : (s == 1) ? W_bb : (s == 2) ? W_lu
                    : (s == 3) ? W_buy : W_li;
    for (int idx = threadIdx.x; idx < 16384; idx += 256) {
      int k = idx >> 7, n = idx & 127;
      int kc = k >> 5, q = (k >> 3) & 3, j = k & 7;
      int nt = n >> 4, nl = n & 15;
      wfrag[((((size_t)s * 4 + kc) * 8 + nt) * 64 + (q * 16 + nl)) * 8 + j] = f2bf(W[idx]);
    }
  }
}

// ---------- CSR scan (3 phases) ----------
__device__ __forceinline__ int block_scan_incl(int v, int* wsum) {
  int lane = threadIdx.x & 63, wid = threadIdx.x >> 6;
#pragma unroll
  for (int d = 1; d < 64; d <<= 1) {
    int n = __shfl_up(v, d, 64);
    if (lane >= d) v += n;
  }
  if (lane == 63) wsum[wid] = v;
  __syncthreads();
  if (threadIdx.x < 4) {
    int s = wsum[threadIdx.x];
#pragma unroll
    for (int d = 1; d < 4; d <<= 1) {
      int n = __shfl_up(s, d, 64);
      if ((int)threadIdx.x >= d) s += n;
    }
    wsum[threadIdx.x] = s;
  }
  __syncthreads();
  return v + (wid ? wsum[wid - 1] : 0);
}

__global__ __launch_bounds__(256) void scan_a(
    int* __restrict__ rp0, int* __restrict__ rp1, int* __restrict__ rp2,
    int* __restrict__ cur0, int* __restrict__ cur1, int* __restrict__ cur2,
    int* __restrict__ bsums) {
  __shared__ int wsum[4];
  int rel = blockIdx.x / SCAN_BLKS;
  int blk = blockIdx.x % SCAN_BLKS;
  int* rp  = (rel == 0) ? rp0  : (rel == 1) ? rp1  : rp2;
  int* cur = (rel == 0) ? cur0 : (rel == 1) ? cur1 : cur2;
  int idx = blk * 256 + threadIdx.x;
  int c = (idx < N_NODES) ? rp[1 + idx] : 0;
  int incl = block_scan_incl(c, wsum);
  if (idx < N_NODES) {
    rp[1 + idx] = incl;
    cur[idx] = incl - c;
  }
  if (threadIdx.x == 255) bsums[rel * 256 + blk] = incl;
}

__global__ __launch_bounds__(256) void scan_b(int* __restrict__ bsums) {
  __shared__ int wsum[4];
  int rel = blockIdx.x;
  int t = threadIdx.x;
  int own = (t < SCAN_BLKS) ? bsums[rel * 256 + t] : 0;
  int incl = block_scan_incl(own, wsum);
  if (t < SCAN_BLKS) bsums[rel * 256 + t] = incl - own;
}

__global__ __launch_bounds__(256) void scan_c(
    int* __restrict__ rp0, int* __restrict__ rp1, int* __restrict__ rp2,
    int* __restrict__ cur0, int* __restrict__ cur1, int* __restrict__ cur2,
    const int* __restrict__ bsums) {
  int rel = blockIdx.x / SCAN_BLKS;
  int blk = blockIdx.x % SCAN_BLKS;
  int* rp  = (rel == 0) ? rp0  : (rel == 1) ? rp1  : rp2;
  int* cur = (rel == 0) ? cur0 : (rel == 1) ? cur1 : cur2;
  int off = bsums[rel * 256 + blk];
  int idx = blk * 256 + threadIdx.x;
  if (idx < N_NODES) {
    rp[1 + idx] += off;
    cur[idx] += off;
  }
}

__global__ __launch_bounds__(256) void fill_kernel(
    const void* __restrict__ e0, const void* __restrict__ e1, const void* __restrict__ e2,
    int* __restrict__ cur0, int* __restrict__ cur1, int* __restrict__ cur2,
    int* __restrict__ csr0, int* __restrict__ csr1, int* __restrict__ csr2,
    const int* __restrict__ flag) {
  int i = blockIdx.x * blockDim.x + threadIdx.x;
  int is64 = *flag;
  if (i < NEDGE) {
    int s0 = edge_at(e0, i, is64), d0 = edge_at(e0, NEDGE + i, is64);
    csr0[atomicAdd(&cur0[d0], 1)] = s0;
    int s1 = edge_at(e1, i, is64), d1 = edge_at(e1, NEDGE + i, is64);
    csr1[atomicAdd(&cur1[d1], 1)] = s1;
    int s2 = edge_at(e2, i, is64), d2 = edge_at(e2, NEDGE + i, is64);
    csr2[atomicAdd(&cur2[d2], 1)] = s2;
  }
}

// ---------- gather-mean aggregation (bf16 in, fp32 accum, bf16 out), all 3 rels ----------
__global__ __launch_bounds__(256) void agg_all(
    const unsigned short* __restrict__ xu_b, const unsigned short* __restrict__ xi_b,
    const int* __restrict__ rp0, const int* __restrict__ rp1, const int* __restrict__ rp2,
    const int* __restrict__ csr0, const int* __restrict__ csr1, const int* __restrict__ csr2,
    unsigned short* __restrict__ aggF, unsigned short* __restrict__ aggBB,
    unsigned short* __restrict__ aggB) {
  int rel = blockIdx.x / 12500;
  int blk = blockIdx.x - rel * 12500;
  const unsigned short* x = (rel == 1) ? xi_b : xu_b;
  const int* rp  = (rel == 0) ? rp0  : (rel == 1) ? rp1  : rp2;
  const int* csr = (rel == 0) ? csr0 : (rel == 1) ? csr1 : csr2;
  unsigned short* agg = (rel == 0) ? aggF : (rel == 1) ? aggBB : aggB;

  int w = (blk * 256 + (int)threadIdx.x) >> 6;   // dst row (exactly 50000 waves/rel)
  int lane = threadIdx.x & 63;
  const unsigned* __restrict__ xv = (const unsigned*)x;  // 64 uints (128 bf16) per row
  int beg = rp[w], end = rp[w + 1];
  float ax = 0.f, ay = 0.f;
  int e = beg;
  for (; e + 3 < end; e += 4) {
    int s0 = csr[e], s1 = csr[e + 1], s2 = csr[e + 2], s3 = csr[e + 3];
    unsigned u0 = xv[(size_t)s0 * 64 + lane];
    unsigned u1 = xv[(size_t)s1 * 64 + lane];
    unsigned u2 = xv[(size_t)s2 * 64 + lane];
    unsigned u3 = xv[(size_t)s3 * 64 + lane];
    ax += bflo(u0) + bflo(u1) + bflo(u2) + bflo(u3);
    ay += bfhi(u0) + bfhi(u1) + bfhi(u2) + bfhi(u3);
  }
  for (; e < end; ++e) {
    unsigned u = xv[(size_t)csr[e] * 64 + lane];
    ax += bflo(u); ay += bfhi(u);
  }
  float rd = 1.0f / fmaxf((float)(end - beg), 1.0f);
  ((unsigned*)agg)[(size_t)w * 64 + lane] =
      (unsigned)f2bf(ax * rd) | ((unsigned)f2bf(ay * rd) << 16);
}

// ---------- MFMA GEMM: out = relu(sum_s A_s @ W_s + bias), both halves ----------
// block: 256 thr (4 waves), 64 rows x 128 cols. A staged in LDS in per-lane
// fragment order (conflict-free ds_read_b128); B fragments read straight from
// global (identical for all blocks -> L2 broadcast).
__global__ __launch_bounds__(256) void mfma_gemm(
    const unsigned short* __restrict__ aggF, const unsigned short* __restrict__ aggBB,
    const unsigned short* __restrict__ aggB,
    const unsigned short* __restrict__ xu, const unsigned short* __restrict__ xi,
    const unsigned short* __restrict__ wfrag,
    const float* __restrict__ b_lu, const float* __restrict__ b_li,
    float* __restrict__ out) {
  __shared__ unsigned short As[8192];   // [rt(4)][kc(4)][lane(64)][8]
  const int t = threadIdx.x;
  const int b = blockIdx.x;
  const int half = (b >= BLK_PER_HALF) ? 1 : 0;
  const int g0 = (half ? b - BLK_PER_HALF : b) * 64;
  const int lane = t & 63;
  const int w = t >> 6;
  const int nsrc = half ? 2 : 3;
  const int widx0 = half ? 3 : 0;

  const unsigned short* A0 = half ? aggB : aggF;
  const unsigned short* A1 = half ? xi   : aggBB;
  const unsigned short* A2 = xu;

  f32x4 acc[4][2] = {};

  for (int s = 0; s < nsrc; ++s) {
    const unsigned short* A = (s == 0) ? A0 : (s == 1) ? A1 : A2;
    // stage 64x128 bf16 A tile into fragment order
#pragma unroll
    for (int i = 0; i < 4; ++i) {
      int idx = t + i * 256;          // 0..1023 chunks of 8 bf16
      int row = idx >> 4;             // 0..63
      int c8 = (idx & 15) << 3;       // 0..120
      int gr = g0 + row;
      float4 v = make_float4(0.f, 0.f, 0.f, 0.f);
      if (gr < N_NODES)
        v = *reinterpret_cast<const float4*>(A + (size_t)gr * FEAT + c8);
      int rt = row >> 4, m = row & 15;
      int kc = c8 >> 5, q = (c8 >> 3) & 3;
      *reinterpret_cast<float4*>(&As[((rt * 4 + kc) * 64 + (q * 16 + m)) * 8]) = v;
    }
    __syncthreads();
    const unsigned short* wf = wfrag + (size_t)(widx0 + s) * (4 * 8 * 64 * 8);
#pragma unroll
    for (int kc = 0; kc < 4; ++kc) {
      short8 bfr[2];
#pragma unroll
      for (int ct = 0; ct < 2; ++ct) {
        int nt = 2 * w + ct;
        bfr[ct] = *reinterpret_cast<const short8*>(wf + ((kc * 8 + nt) * 64 + lane) * 8);
      }
#pragma unroll
      for (int rt = 0; rt < 4; ++rt) {
        short8 afr = *reinterpret_cast<const short8*>(&As[((rt * 4 + kc) * 64 + lane) * 8]);
#pragma unroll
        for (int ct = 0; ct < 2; ++ct)
          acc[rt][ct] = __builtin_amdgcn_mfma_f32_16x16x32_bf16(afr, bfr[ct],
                                                                acc[rt][ct], 0, 0, 0);
      }
    }
    __syncthreads();
  }

  // epilogue: C/D layout col=lane&15, row=quad*4+r
  const float* bias = half ? b_li : b_lu;
  int q = lane >> 4, nl = lane & 15;
  float bv[2] = { bias[w * 32 + nl], bias[w * 32 + 16 + nl] };
#pragma unroll
  for (int rt = 0; rt < 4; ++rt)
#pragma unroll
    for (int r = 0; r < 4; ++r) {
      int gr = g0 + rt * 16 + q * 4 + r;
      if (gr < N_NODES) {
        size_t orow = (size_t)(half ? N_NODES : 0) + gr;
#pragma unroll
        for (int ct = 0; ct < 2; ++ct) {
          float v = acc[rt][ct][r] + bv[ct];
          out[orow * FEAT + w * 32 + ct * 16 + nl] = fmaxf(v, 0.f);
        }
      }
    }
}

extern "C" void kernel_launch(void* const* d_in, const int* in_sizes, int n_in,
                              void* d_out, int out_size, void* d_ws, size_t ws_size,
                              hipStream_t stream) {
  const float* x_user = (const float*)d_in[0];
  const float* x_item = (const float*)d_in[1];
  const void* e_fol = d_in[2];
  const void* e_buy = d_in[3];
  const void* e_bb  = d_in[4];
  const float* W_fol = (const float*)d_in[5];
  const float* W_buy = (const float*)d_in[6];
  const float* W_bb  = (const float*)d_in[7];
  const float* W_lu  = (const float*)d_in[8];
  const float* b_lu  = (const float*)d_in[9];
  const float* W_li  = (const float*)d_in[10];
  const float* b_li  = (const float*)d_in[11];
  float* out = (float*)d_out;

  // ws layout: bf16 arrays first, then ints (total ~72.6 MB; big path >=85MB confirmed)
  unsigned short* wsu = (unsigned short*)d_ws;
  unsigned short* aggF  = wsu;
  unsigned short* aggBB = wsu + 6400000;
  unsigned short* aggB  = wsu + 12800000;
  unsigned short* xu_b  = wsu + 19200000;
  unsigned short* xi_b  = wsu + 25600000;
  unsigned short* wfrag = wsu + 32000000;      // 5*4*8*64*8 = 81920 ushorts
  int* ip = (int*)d_ws + 16040960;             // byte offset 64,163,840
  int* csr0 = ip;
  int* csr1 = ip + 600000;
  int* csr2 = ip + 1200000;
  int* rp0  = ip + 1800000;     // 50016 each
  int* rp1  = rp0 + 50016;
  int* rp2  = rp1 + 50016;
  int* cur0 = ip + 1950048;     // 50000 each
  int* cur1 = cur0 + 50000;
  int* cur2 = cur1 + 50000;
  int* bsums = ip + 2100048;    // 3 x 256
  int* flag  = ip + 2100816;

  hipMemsetAsync(rp0, 0, 150048ull * sizeof(int), stream);
  detect_i64<<<1, 64, 0, stream>>>((const unsigned int*)e_fol, flag);

  hist_cvt<<<NB_HIST + NB_CVT + NB_W, 256, 0, stream>>>(
      e_fol, e_bb, e_buy, rp0, rp1, rp2, x_user, x_item,
      W_fol, W_bb, W_lu, W_buy, W_li, xu_b, xi_b, wfrag, flag);

  scan_a<<<3 * SCAN_BLKS, 256, 0, stream>>>(rp0, rp1, rp2, cur0, cur1, cur2, bsums);
  scan_b<<<3, 256, 0, stream>>>(bsums);
  scan_c<<<3 * SCAN_BLKS, 256, 0, stream>>>(rp0, rp1, rp2, cur0, cur1, cur2, bsums);
  fill_kernel<<<NB_HIST, 256, 0, stream>>>(e_fol, e_bb, e_buy, cur0, cur1, cur2,
                                           csr0, csr1, csr2, flag);

  agg_all<<<3 * 12500, 256, 0, stream>>>(xu_b, xi_b, rp0, rp1, rp2,
                                         csr0, csr1, csr2, aggF, aggBB, aggB);

  mfma_gemm<<<2 * BLK_PER_HALF, 256, 0, stream>>>(
      aggF, aggBB, aggB, xu_b, xi_b, wfrag, b_lu, b_li, out);
}

// Round 6
// 395.454 us; speedup vs baseline: 2.8080x; 1.1477x over previous
//
#include <hip/hip_runtime.h>

#define N_NODES 50000
#define FEAT    128
#define NEDGE   600000
#define BLK_PER_HALF 782   // ceil(50000/64)

#define NBUK   196         // buckets per rel, 256 dsts each (196*256 = 50176)
#define BUKCAP 4096        // mean 3061, sigma 55 -> 19-sigma headroom
#define NB_PART 2344       // ceil(600000/256), 3 rels per thread
#define NB_CVT  6250       // 2 x 3125
#define NB_W    5

typedef __attribute__((ext_vector_type(8))) short short8;
typedef __attribute__((ext_vector_type(4))) float f32x4;

// ---------- bf16 helpers ----------
__device__ __forceinline__ unsigned short f2bf(float f) {
  unsigned u = __float_as_uint(f);
  return (unsigned short)((u + 0x7fffu + ((u >> 16) & 1u)) >> 16);
}
__device__ __forceinline__ float bflo(unsigned u) { return __uint_as_float(u << 16); }
__device__ __forceinline__ float bfhi(unsigned u) { return __uint_as_float(u & 0xffff0000u); }

// ---------- edge dtype handling ----------
__global__ void detect_i64(const unsigned int* __restrict__ e, int* __restrict__ flag) {
  unsigned int hi = e[2 * threadIdx.x + 1];
  unsigned long long any = __ballot(hi != 0u);
  if (threadIdx.x == 0) flag[0] = (any == 0ull) ? 1 : 0;
}
__device__ __forceinline__ int edge_at(const void* __restrict__ edges, long i, int is64) {
  return is64 ? (int)((const long long*)edges)[i] : ((const int*)edges)[i];
}

// ---------- fused: bucket partition + x->bf16 conversion + W fragment pack ----------
// partition: entry = src | (dst&255)<<16 appended to fixed-cap bucket region.
// counters padded to one 64B line each -> hot-line atomics; stores cluster in time.
__global__ __launch_bounds__(256) void part_cvt(
    const void* __restrict__ e0, const void* __restrict__ e1, const void* __restrict__ e2,
    unsigned* __restrict__ part, int* __restrict__ bcur,
    const float* __restrict__ xu, const float* __restrict__ xi,
    const float* __restrict__ W_fol, const float* __restrict__ W_bb,
    const float* __restrict__ W_lu, const float* __restrict__ W_buy,
    const float* __restrict__ W_li,
    unsigned short* __restrict__ xu_b, unsigned short* __restrict__ xi_b,
    unsigned short* __restrict__ wfrag, const int* __restrict__ flag) {
  int b = blockIdx.x;
  if (b < NB_PART) {
    int i = b * 256 + threadIdx.x;
    int is64 = *flag;
    if (i < NEDGE) {
      const void* es[3] = {e0, e1, e2};
#pragma unroll
      for (int rel = 0; rel < 3; ++rel) {
        int src = edge_at(es[rel], i, is64);
        int dst = edge_at(es[rel], NEDGE + i, is64);
        int bk = rel * NBUK + (dst >> 8);
        int pos = atomicAdd(&bcur[bk * 16], 1);
        if (pos < BUKCAP)
          part[((size_t)bk << 12) + pos] = (unsigned)src | ((unsigned)(dst & 255) << 16);
      }
    }
  } else if (b < NB_PART + NB_CVT) {
    int cb = b - NB_PART;
    const float* src = (cb < 3125) ? xu : xi;
    unsigned short* dst = (cb < 3125) ? xu_b : xi_b;
    int lb = (cb < 3125) ? cb : cb - 3125;
    size_t base = ((size_t)lb * 256 + threadIdx.x) * 8;
    float4 v0 = *reinterpret_cast<const float4*>(src + base);
    float4 v1 = *reinterpret_cast<const float4*>(src + base + 4);
    uint4 o;
    o.x = f2bf(v0.x) | ((unsigned)f2bf(v0.y) << 16);
    o.y = f2bf(v0.z) | ((unsigned)f2bf(v0.w) << 16);
    o.z = f2bf(v1.x) | ((unsigned)f2bf(v1.y) << 16);
    o.w = f2bf(v1.z) | ((unsigned)f2bf(v1.w) << 16);
    *reinterpret_cast<uint4*>(dst + base) = o;
  } else {
    int s = b - (NB_PART + NB_CVT);
    const float* W = (s == 0) ? W_fol : (s == 1) ? W_bb : (s == 2) ? W_lu
                    : (s == 3) ? W_buy : W_li;
    for (int idx = threadIdx.x; idx < 16384; idx += 256) {
      int k = idx >> 7, n = idx & 127;
      int kc = k >> 5, q = (k >> 3) & 3, j = k & 7;
      int nt = n >> 4, nl = n & 15;
      wfrag[((((size_t)s * 4 + kc) * 8 + nt) * 64 + (q * 16 + nl)) * 8 + j] = f2bf(W[idx]);
    }
  }
}

// ---------- block scan helper ----------
__device__ __forceinline__ int block_scan_incl(int v, int* wsum) {
  int lane = threadIdx.x & 63, wid = threadIdx.x >> 6;
#pragma unroll
  for (int d = 1; d < 64; d <<= 1) {
    int n = __shfl_up(v, d, 64);
    if (lane >= d) v += n;
  }
  if (lane == 63) wsum[wid] = v;
  __syncthreads();
  if (threadIdx.x < 4) {
    int s = wsum[threadIdx.x];
#pragma unroll
    for (int d = 1; d < 4; d <<= 1) {
      int n = __shfl_up(s, d, 64);
      if ((int)threadIdx.x >= d) s += n;
    }
    wsum[threadIdx.x] = s;
  }
  __syncthreads();
  return v + (wid ? wsum[wid - 1] : 0);
}

// ---------- bucket bases: exclusive scan of 196 counts per rel (1 block) ----------
__global__ __launch_bounds__(256) void bucket_scan(
    const int* __restrict__ bcur, int* __restrict__ bbase,
    int* __restrict__ rp0, int* __restrict__ rp1, int* __restrict__ rp2) {
  __shared__ int wsum[4];
  for (int rel = 0; rel < 3; ++rel) {
    __syncthreads();
    int t = threadIdx.x;
    int c = (t < NBUK) ? min(bcur[(rel * NBUK + t) * 16], BUKCAP) : 0;
    int incl = block_scan_incl(c, wsum);
    if (t < NBUK) bbase[rel * NBUK + t] = incl - c;
  }
  if (threadIdx.x == 0) {
    rp0[N_NODES] = NEDGE; rp1[N_NODES] = NEDGE; rp2[N_NODES] = NEDGE;
  }
}

// ---------- per-bucket CSR build: all-coalesced global traffic ----------
__global__ __launch_bounds__(256) void csr_build(
    const unsigned* __restrict__ part, const int* __restrict__ bcur,
    const int* __restrict__ bbase,
    int* __restrict__ csr0, int* __restrict__ csr1, int* __restrict__ csr2,
    int* __restrict__ rp0, int* __restrict__ rp1, int* __restrict__ rp2) {
  __shared__ int cnt[256];
  __shared__ int curs[256];
  __shared__ int wsum[4];
  __shared__ unsigned short img[BUKCAP];
  int blk = blockIdx.x;
  int rel = blk / NBUK, lb = blk - rel * NBUK;
  int* __restrict__ csr = (rel == 0) ? csr0 : (rel == 1) ? csr1 : csr2;
  int* __restrict__ rp  = (rel == 0) ? rp0  : (rel == 1) ? rp1  : rp2;
  int n = min(bcur[blk * 16], BUKCAP);
  int base = bbase[blk];
  const unsigned* __restrict__ ent = part + ((size_t)blk << 12);
  int t = threadIdx.x;

  cnt[t] = 0;
  __syncthreads();
  for (int i = t; i < n; i += 256)
    atomicAdd(&cnt[(ent[i] >> 16) & 255], 1);
  __syncthreads();
  int c = cnt[t];
  int incl = block_scan_incl(c, wsum);
  int excl = incl - c;
  curs[t] = excl;
  int d = lb * 256 + t;
  if (d < N_NODES) rp[d] = base + excl;
  __syncthreads();
  for (int i = t; i < n; i += 256) {
    unsigned en = ent[i];
    int pos = atomicAdd(&curs[(en >> 16) & 255], 1);
    img[pos] = (unsigned short)(en & 0xffffu);
  }
  __syncthreads();
  for (int i = t; i < n; i += 256)
    csr[base + i] = (int)img[i];
}

// ---------- gather-mean aggregation (bf16 in, fp32 accum, bf16 out) ----------
__global__ __launch_bounds__(256) void agg_all(
    const unsigned short* __restrict__ xu_b, const unsigned short* __restrict__ xi_b,
    const int* __restrict__ rp0, const int* __restrict__ rp1, const int* __restrict__ rp2,
    const int* __restrict__ csr0, const int* __restrict__ csr1, const int* __restrict__ csr2,
    unsigned short* __restrict__ aggF, unsigned short* __restrict__ aggBB,
    unsigned short* __restrict__ aggB) {
  int rel = blockIdx.x / 12500;
  int blk = blockIdx.x - rel * 12500;
  const unsigned short* x = (rel == 1) ? xi_b : xu_b;
  const int* rp  = (rel == 0) ? rp0  : (rel == 1) ? rp1  : rp2;
  const int* csr = (rel == 0) ? csr0 : (rel == 1) ? csr1 : csr2;
  unsigned short* agg = (rel == 0) ? aggF : (rel == 1) ? aggBB : aggB;

  int w = (blk * 256 + (int)threadIdx.x) >> 6;
  int lane = threadIdx.x & 63;
  const unsigned* __restrict__ xv = (const unsigned*)x;
  int beg = rp[w], end = rp[w + 1];
  float ax = 0.f, ay = 0.f;
  int e = beg;
  for (; e + 3 < end; e += 4) {
    int s0 = csr[e], s1 = csr[e + 1], s2 = csr[e + 2], s3 = csr[e + 3];
    unsigned u0 = xv[(size_t)s0 * 64 + lane];
    unsigned u1 = xv[(size_t)s1 * 64 + lane];
    unsigned u2 = xv[(size_t)s2 * 64 + lane];
    unsigned u3 = xv[(size_t)s3 * 64 + lane];
    ax += bflo(u0) + bflo(u1) + bflo(u2) + bflo(u3);
    ay += bfhi(u0) + bfhi(u1) + bfhi(u2) + bfhi(u3);
  }
  for (; e < end; ++e) {
    unsigned u = xv[(size_t)csr[e] * 64 + lane];
    ax += bflo(u); ay += bfhi(u);
  }
  float rd = 1.0f / fmaxf((float)(end - beg), 1.0f);
  ((unsigned*)agg)[(size_t)w * 64 + lane] =
      (unsigned)f2bf(ax * rd) | ((unsigned)f2bf(ay * rd) << 16);
}

// ---------- MFMA GEMM: out = relu(sum_s A_s @ W_s + bias), both halves ----------
__global__ __launch_bounds__(256) void mfma_gemm(
    const unsigned short* __restrict__ aggF, const unsigned short* __restrict__ aggBB,
    const unsigned short* __restrict__ aggB,
    const unsigned short* __restrict__ xu, const unsigned short* __restrict__ xi,
    const unsigned short* __restrict__ wfrag,
    const float* __restrict__ b_lu, const float* __restrict__ b_li,
    float* __restrict__ out) {
  __shared__ unsigned short As[8192];   // [rt(4)][kc(4)][lane(64)][8]
  const int t = threadIdx.x;
  const int b = blockIdx.x;
  const int half = (b >= BLK_PER_HALF) ? 1 : 0;
  const int g0 = (half ? b - BLK_PER_HALF : b) * 64;
  const int lane = t & 63;
  const int w = t >> 6;
  const int nsrc = half ? 2 : 3;
  const int widx0 = half ? 3 : 0;

  const unsigned short* A0 = half ? aggB : aggF;
  const unsigned short* A1 = half ? xi   : aggBB;
  const unsigned short* A2 = xu;

  f32x4 acc[4][2] = {};

  for (int s = 0; s < nsrc; ++s) {
    const unsigned short* A = (s == 0) ? A0 : (s == 1) ? A1 : A2;
#pragma unroll
    for (int i = 0; i < 4; ++i) {
      int idx = t + i * 256;
      int row = idx >> 4;
      int c8 = (idx & 15) << 3;
      int gr = g0 + row;
      float4 v = make_float4(0.f, 0.f, 0.f, 0.f);
      if (gr < N_NODES)
        v = *reinterpret_cast<const float4*>(A + (size_t)gr * FEAT + c8);
      int rt = row >> 4, m = row & 15;
      int kc = c8 >> 5, q = (c8 >> 3) & 3;
      *reinterpret_cast<float4*>(&As[((rt * 4 + kc) * 64 + (q * 16 + m)) * 8]) = v;
    }
    __syncthreads();
    const unsigned short* wf = wfrag + (size_t)(widx0 + s) * (4 * 8 * 64 * 8);
#pragma unroll
    for (int kc = 0; kc < 4; ++kc) {
      short8 bfr[2];
#pragma unroll
      for (int ct = 0; ct < 2; ++ct) {
        int nt = 2 * w + ct;
        bfr[ct] = *reinterpret_cast<const short8*>(wf + ((kc * 8 + nt) * 64 + lane) * 8);
      }
#pragma unroll
      for (int rt = 0; rt < 4; ++rt) {
        short8 afr = *reinterpret_cast<const short8*>(&As[((rt * 4 + kc) * 64 + lane) * 8]);
#pragma unroll
        for (int ct = 0; ct < 2; ++ct)
          acc[rt][ct] = __builtin_amdgcn_mfma_f32_16x16x32_bf16(afr, bfr[ct],
                                                                acc[rt][ct], 0, 0, 0);
      }
    }
    __syncthreads();
  }

  const float* bias = half ? b_li : b_lu;
  int q = lane >> 4, nl = lane & 15;
  float bv[2] = { bias[w * 32 + nl], bias[w * 32 + 16 + nl] };
#pragma unroll
  for (int rt = 0; rt < 4; ++rt)
#pragma unroll
    for (int r = 0; r < 4; ++r) {
      int gr = g0 + rt * 16 + q * 4 + r;
      if (gr < N_NODES) {
        size_t orow = (size_t)(half ? N_NODES : 0) + gr;
#pragma unroll
        for (int ct = 0; ct < 2; ++ct) {
          float v = acc[rt][ct][r] + bv[ct];
          out[orow * FEAT + w * 32 + ct * 16 + nl] = fmaxf(v, 0.f);
        }
      }
    }
}

extern "C" void kernel_launch(void* const* d_in, const int* in_sizes, int n_in,
                              void* d_out, int out_size, void* d_ws, size_t ws_size,
                              hipStream_t stream) {
  const float* x_user = (const float*)d_in[0];
  const float* x_item = (const float*)d_in[1];
  const void* e_fol = d_in[2];
  const void* e_buy = d_in[3];
  const void* e_bb  = d_in[4];
  const float* W_fol = (const float*)d_in[5];
  const float* W_buy = (const float*)d_in[6];
  const float* W_bb  = (const float*)d_in[7];
  const float* W_lu  = (const float*)d_in[8];
  const float* b_lu  = (const float*)d_in[9];
  const float* W_li  = (const float*)d_in[10];
  const float* b_li  = (const float*)d_in[11];
  float* out = (float*)d_out;

  // ws layout: bf16 arrays (64.16 MB) then ints (17.5 MB); total 81.7 MB (<85.2 known)
  unsigned short* wsu = (unsigned short*)d_ws;
  unsigned short* aggF  = wsu;
  unsigned short* aggBB = wsu + 6400000;
  unsigned short* aggB  = wsu + 12800000;
  unsigned short* xu_b  = wsu + 19200000;
  unsigned short* xi_b  = wsu + 25600000;
  unsigned short* wfrag = wsu + 32000000;      // 81920 ushorts
  int* ip = (int*)d_ws + 16040960;
  int* csr0 = ip;
  int* csr1 = ip + 600000;
  int* csr2 = ip + 1200000;
  int* rp0  = ip + 1800000;     // 50016 each
  int* rp1  = rp0 + 50016;
  int* rp2  = rp1 + 50016;
  unsigned* part = (unsigned*)(ip + 1950048);  // 588*4096 = 2408448
  int* bcur  = ip + 4358496;    // 588*16 (padded counters)
  int* bbase = ip + 4367904;    // 588
  int* flag  = ip + 4368492;

  hipMemsetAsync(bcur, 0, 9408ull * sizeof(int), stream);
  detect_i64<<<1, 64, 0, stream>>>((const unsigned int*)e_fol, flag);

  part_cvt<<<NB_PART + NB_CVT + NB_W, 256, 0, stream>>>(
      e_fol, e_bb, e_buy, part, bcur, x_user, x_item,
      W_fol, W_bb, W_lu, W_buy, W_li, xu_b, xi_b, wfrag, flag);

  bucket_scan<<<1, 256, 0, stream>>>(bcur, bbase, rp0, rp1, rp2);

  csr_build<<<3 * NBUK, 256, 0, stream>>>(part, bcur, bbase,
                                          csr0, csr1, csr2, rp0, rp1, rp2);

  agg_all<<<3 * 12500, 256, 0, stream>>>(xu_b, xi_b, rp0, rp1, rp2,
                                         csr0, csr1, csr2, aggF, aggBB, aggB);

  mfma_gemm<<<2 * BLK_PER_HALF, 256, 0, stream>>>(
      aggF, aggBB, aggB, xu_b, xi_b, wfrag, b_lu, b_li, out);
}

// Round 7
// 370.884 us; speedup vs baseline: 2.9940x; 1.0662x over previous
//
#include <hip/hip_runtime.h>

#define N_NODES 50000
#define FEAT    128
#define NEDGE   600000
#define BLK_PER_HALF 782   // ceil(50000/64)

#define NBUK    196        // buckets per rel (256 dsts each); 588 total
#define NBUKT   588
#define BUKCAP  4096       // bucket total: mean 3061, sigma 55 -> 19 sigma
#define KPART   64         // partition blocks (private regions)
#define SEGCAP  128        // per (block,bucket) entries: mean 47.8, 11.6 sigma
#define EPB     9375       // 600000 / 64 edges per partition block
#define NB_CVT  6250       // 2 x 3125
#define NB_W    5

typedef __attribute__((ext_vector_type(8))) short short8;
typedef __attribute__((ext_vector_type(4))) float f32x4;

// ---------- bf16 helpers ----------
__device__ __forceinline__ unsigned short f2bf(float f) {
  unsigned u = __float_as_uint(f);
  return (unsigned short)((u + 0x7fffu + ((u >> 16) & 1u)) >> 16);
}
__device__ __forceinline__ float bflo(unsigned u) { return __uint_as_float(u << 16); }
__device__ __forceinline__ float bfhi(unsigned u) { return __uint_as_float(u & 0xffff0000u); }

// ---------- edge dtype handling ----------
__global__ void detect_i64(const unsigned int* __restrict__ e, int* __restrict__ flag) {
  unsigned int hi = e[2 * threadIdx.x + 1];
  unsigned long long any = __ballot(hi != 0u);
  if (threadIdx.x == 0) flag[0] = (any == 0ull) ? 1 : 0;
}
__device__ __forceinline__ int edge_at(const void* __restrict__ edges, long i, int is64) {
  return is64 ? (int)((const long long*)edges)[i] : ((const int*)edges)[i];
}

// ---------- fused: private-region partition + x->bf16 conversion + W pack ----------
// blocks [0,64): partition with LDS counters + block-private append regions
// (zero global atomics; region lines are XCD-private -> no line bouncing).
__global__ __launch_bounds__(256) void part_cvt(
    const void* __restrict__ e0, const void* __restrict__ e1, const void* __restrict__ e2,
    unsigned* __restrict__ part, int* __restrict__ counts,
    const float* __restrict__ xu, const float* __restrict__ xi,
    const float* __restrict__ W_fol, const float* __restrict__ W_bb,
    const float* __restrict__ W_lu, const float* __restrict__ W_buy,
    const float* __restrict__ W_li,
    unsigned short* __restrict__ xu_b, unsigned short* __restrict__ xi_b,
    unsigned short* __restrict__ wfrag, const int* __restrict__ flag) {
  __shared__ int scnt[NBUKT];
  int b = blockIdx.x;
  int t = threadIdx.x;
  if (b < KPART) {
    for (int i = t; i < NBUKT; i += 256) scnt[i] = 0;
    __syncthreads();
    int is64 = *flag;
    const void* es[3] = {e0, e1, e2};
    int ebase = b * EPB;
    for (int i = t; i < EPB; i += 256) {
      int ei = ebase + i;
#pragma unroll
      for (int rel = 0; rel < 3; ++rel) {
        int src = edge_at(es[rel], ei, is64);
        int dst = edge_at(es[rel], NEDGE + ei, is64);
        int bk = rel * NBUK + (dst >> 8);
        int pos = atomicAdd(&scnt[bk], 1);
        if (pos < SEGCAP)
          part[(((size_t)b * NBUKT + bk) << 7) + pos] =
              (unsigned)src | ((unsigned)(dst & 255) << 16);
      }
    }
    __syncthreads();
    for (int i = t; i < NBUKT; i += 256) counts[b * NBUKT + i] = min(scnt[i], SEGCAP);
  } else if (b < KPART + NB_CVT) {
    int cb = b - KPART;
    const float* src = (cb < 3125) ? xu : xi;
    unsigned short* dst = (cb < 3125) ? xu_b : xi_b;
    int lb = (cb < 3125) ? cb : cb - 3125;
    size_t base = ((size_t)lb * 256 + t) * 8;
    float4 v0 = *reinterpret_cast<const float4*>(src + base);
    float4 v1 = *reinterpret_cast<const float4*>(src + base + 4);
    uint4 o;
    o.x = f2bf(v0.x) | ((unsigned)f2bf(v0.y) << 16);
    o.y = f2bf(v0.z) | ((unsigned)f2bf(v0.w) << 16);
    o.z = f2bf(v1.x) | ((unsigned)f2bf(v1.y) << 16);
    o.w = f2bf(v1.z) | ((unsigned)f2bf(v1.w) << 16);
    *reinterpret_cast<uint4*>(dst + base) = o;
  } else {
    int s = b - (KPART + NB_CVT);
    const float* W = (s == 0) ? W_fol : (s == 1) ? W_bb : (s == 2) ? W_lu
                    : (s == 3) ? W_buy : W_li;
    for (int idx = t; idx < 16384; idx += 256) {
      int k = idx >> 7, n = idx & 127;
      int kc = k >> 5, q = (k >> 3) & 3, j = k & 7;
      int nt = n >> 4, nl = n & 15;
      wfrag[((((size_t)s * 4 + kc) * 8 + nt) * 64 + (q * 16 + nl)) * 8 + j] = f2bf(W[idx]);
    }
  }
}

// ---------- block scan helper ----------
__device__ __forceinline__ int block_scan_incl(int v, int* wsum) {
  int lane = threadIdx.x & 63, wid = threadIdx.x >> 6;
#pragma unroll
  for (int d = 1; d < 64; d <<= 1) {
    int n = __shfl_up(v, d, 64);
    if (lane >= d) v += n;
  }
  if (lane == 63) wsum[wid] = v;
  __syncthreads();
  if (threadIdx.x < 4) {
    int s = wsum[threadIdx.x];
#pragma unroll
    for (int d = 1; d < 4; d <<= 1) {
      int n = __shfl_up(s, d, 64);
      if ((int)threadIdx.x >= d) s += n;
    }
    wsum[threadIdx.x] = s;
  }
  __syncthreads();
  return v + (wid ? wsum[wid - 1] : 0);
}

// ---------- bucket totals + per-rel exclusive scan (1 block) ----------
__global__ __launch_bounds__(256) void bucket_scan(
    const int* __restrict__ counts, int* __restrict__ bbase,
    int* __restrict__ rp0, int* __restrict__ rp1, int* __restrict__ rp2) {
  __shared__ int tot[NBUKT];
  __shared__ int wsum[4];
  int t = threadIdx.x;
  for (int base = 0; base < NBUKT; base += 256) {
    int bk = base + t;
    if (bk < NBUKT) {
      int r = 0;
      for (int k = 0; k < KPART; ++k) r += counts[k * NBUKT + bk];
      tot[bk] = min(r, BUKCAP);
    }
  }
  __syncthreads();
  for (int rel = 0; rel < 3; ++rel) {
    int c = (t < NBUK) ? tot[rel * NBUK + t] : 0;
    int incl = block_scan_incl(c, wsum);
    if (t < NBUK) bbase[rel * NBUK + t] = incl - c;
    __syncthreads();
  }
  if (t == 0) {
    rp0[N_NODES] = NEDGE; rp1[N_NODES] = NEDGE; rp2[N_NODES] = NEDGE;
  }
}

// ---------- per-bucket CSR build from 64 private segments ----------
__global__ __launch_bounds__(256) void csr_build(
    const unsigned* __restrict__ part, const int* __restrict__ counts,
    const int* __restrict__ bbase,
    int* __restrict__ csr0, int* __restrict__ csr1, int* __restrict__ csr2,
    int* __restrict__ rp0, int* __restrict__ rp1, int* __restrict__ rp2) {
  __shared__ int cnt[256];
  __shared__ int curs[256];
  __shared__ int wsum[4];
  __shared__ unsigned short img[BUKCAP];
  int blk = blockIdx.x;
  int rel = blk / NBUK, lb = blk - rel * NBUK;
  int* __restrict__ csr = (rel == 0) ? csr0 : (rel == 1) ? csr1 : csr2;
  int* __restrict__ rp  = (rel == 0) ? rp0  : (rel == 1) ? rp1  : rp2;
  int base = bbase[blk];
  int t = threadIdx.x;

  cnt[t] = 0;
  __syncthreads();
  int n = 0;
  for (int k = 0; k < KPART; ++k) {
    int ck = counts[k * NBUKT + blk];
    const unsigned* __restrict__ ent = part + (((size_t)k * NBUKT + blk) << 7);
    for (int i = t; i < ck; i += 256)
      atomicAdd(&cnt[(ent[i] >> 16) & 255], 1);
    n += ck;
  }
  n = min(n, BUKCAP);
  __syncthreads();
  int c = cnt[t];
  int incl = block_scan_incl(c, wsum);
  int excl = incl - c;
  curs[t] = excl;
  int d = lb * 256 + t;
  if (d < N_NODES) rp[d] = base + excl;
  __syncthreads();
  for (int k = 0; k < KPART; ++k) {
    int ck = counts[k * NBUKT + blk];
    const unsigned* __restrict__ ent = part + (((size_t)k * NBUKT + blk) << 7);
    for (int i = t; i < ck; i += 256) {
      unsigned en = ent[i];
      int pos = atomicAdd(&curs[(en >> 16) & 255], 1);
      if (pos < BUKCAP) img[pos] = (unsigned short)(en & 0xffffu);
    }
  }
  __syncthreads();
  for (int i = t; i < n; i += 256)
    csr[base + i] = (int)img[i];
}

// ---------- gather-mean aggregation (bf16 in, fp32 accum, bf16 out) ----------
__global__ __launch_bounds__(256) void agg_all(
    const unsigned short* __restrict__ xu_b, const unsigned short* __restrict__ xi_b,
    const int* __restrict__ rp0, const int* __restrict__ rp1, const int* __restrict__ rp2,
    const int* __restrict__ csr0, const int* __restrict__ csr1, const int* __restrict__ csr2,
    unsigned short* __restrict__ aggF, unsigned short* __restrict__ aggBB,
    unsigned short* __restrict__ aggB) {
  int rel = blockIdx.x / 12500;
  int blk = blockIdx.x - rel * 12500;
  const unsigned short* x = (rel == 1) ? xi_b : xu_b;
  const int* rp  = (rel == 0) ? rp0  : (rel == 1) ? rp1  : rp2;
  const int* csr = (rel == 0) ? csr0 : (rel == 1) ? csr1 : csr2;
  unsigned short* agg = (rel == 0) ? aggF : (rel == 1) ? aggBB : aggB;

  int w = (blk * 256 + (int)threadIdx.x) >> 6;
  int lane = threadIdx.x & 63;
  const unsigned* __restrict__ xv = (const unsigned*)x;
  int beg = rp[w], end = rp[w + 1];
  float ax = 0.f, ay = 0.f;
  int e = beg;
  for (; e + 3 < end; e += 4) {
    int s0 = csr[e], s1 = csr[e + 1], s2 = csr[e + 2], s3 = csr[e + 3];
    unsigned u0 = xv[(size_t)s0 * 64 + lane];
    unsigned u1 = xv[(size_t)s1 * 64 + lane];
    unsigned u2 = xv[(size_t)s2 * 64 + lane];
    unsigned u3 = xv[(size_t)s3 * 64 + lane];
    ax += bflo(u0) + bflo(u1) + bflo(u2) + bflo(u3);
    ay += bfhi(u0) + bfhi(u1) + bfhi(u2) + bfhi(u3);
  }
  for (; e < end; ++e) {
    unsigned u = xv[(size_t)csr[e] * 64 + lane];
    ax += bflo(u); ay += bfhi(u);
  }
  float rd = 1.0f / fmaxf((float)(end - beg), 1.0f);
  ((unsigned*)agg)[(size_t)w * 64 + lane] =
      (unsigned)f2bf(ax * rd) | ((unsigned)f2bf(ay * rd) << 16);
}

// ---------- MFMA GEMM: out = relu(sum_s A_s @ W_s + bias), both halves ----------
__global__ __launch_bounds__(256) void mfma_gemm(
    const unsigned short* __restrict__ aggF, const unsigned short* __restrict__ aggBB,
    const unsigned short* __restrict__ aggB,
    const unsigned short* __restrict__ xu, const unsigned short* __restrict__ xi,
    const unsigned short* __restrict__ wfrag,
    const float* __restrict__ b_lu, const float* __restrict__ b_li,
    float* __restrict__ out) {
  __shared__ unsigned short As[8192];   // [rt(4)][kc(4)][lane(64)][8]
  const int t = threadIdx.x;
  const int b = blockIdx.x;
  const int half = (b >= BLK_PER_HALF) ? 1 : 0;
  const int g0 = (half ? b - BLK_PER_HALF : b) * 64;
  const int lane = t & 63;
  const int w = t >> 6;
  const int nsrc = half ? 2 : 3;
  const int widx0 = half ? 3 : 0;

  const unsigned short* A0 = half ? aggB : aggF;
  const unsigned short* A1 = half ? xi   : aggBB;
  const unsigned short* A2 = xu;

  f32x4 acc[4][2] = {};

  for (int s = 0; s < nsrc; ++s) {
    const unsigned short* A = (s == 0) ? A0 : (s == 1) ? A1 : A2;
#pragma unroll
    for (int i = 0; i < 4; ++i) {
      int idx = t + i * 256;
      int row = idx >> 4;
      int c8 = (idx & 15) << 3;
      int gr = g0 + row;
      float4 v = make_float4(0.f, 0.f, 0.f, 0.f);
      if (gr < N_NODES)
        v = *reinterpret_cast<const float4*>(A + (size_t)gr * FEAT + c8);
      int rt = row >> 4, m = row & 15;
      int kc = c8 >> 5, q = (c8 >> 3) & 3;
      *reinterpret_cast<float4*>(&As[((rt * 4 + kc) * 64 + (q * 16 + m)) * 8]) = v;
    }
    __syncthreads();
    const unsigned short* wf = wfrag + (size_t)(widx0 + s) * (4 * 8 * 64 * 8);
#pragma unroll
    for (int kc = 0; kc < 4; ++kc) {
      short8 bfr[2];
#pragma unroll
      for (int ct = 0; ct < 2; ++ct) {
        int nt = 2 * w + ct;
        bfr[ct] = *reinterpret_cast<const short8*>(wf + ((kc * 8 + nt) * 64 + lane) * 8);
      }
#pragma unroll
      for (int rt = 0; rt < 4; ++rt) {
        short8 afr = *reinterpret_cast<const short8*>(&As[((rt * 4 + kc) * 64 + lane) * 8]);
#pragma unroll
        for (int ct = 0; ct < 2; ++ct)
          acc[rt][ct] = __builtin_amdgcn_mfma_f32_16x16x32_bf16(afr, bfr[ct],
                                                                acc[rt][ct], 0, 0, 0);
      }
    }
    __syncthreads();
  }

  const float* bias = half ? b_li : b_lu;
  int q = lane >> 4, nl = lane & 15;
  float bv[2] = { bias[w * 32 + nl], bias[w * 32 + 16 + nl] };
#pragma unroll
  for (int rt = 0; rt < 4; ++rt)
#pragma unroll
    for (int r = 0; r < 4; ++r) {
      int gr = g0 + rt * 16 + q * 4 + r;
      if (gr < N_NODES) {
        size_t orow = (size_t)(half ? N_NODES : 0) + gr;
#pragma unroll
        for (int ct = 0; ct < 2; ++ct) {
          float v = acc[rt][ct][r] + bv[ct];
          out[orow * FEAT + w * 32 + ct * 16 + nl] = fmaxf(v, 0.f);
        }
      }
    }
}

extern "C" void kernel_launch(void* const* d_in, const int* in_sizes, int n_in,
                              void* d_out, int out_size, void* d_ws, size_t ws_size,
                              hipStream_t stream) {
  const float* x_user = (const float*)d_in[0];
  const float* x_item = (const float*)d_in[1];
  const void* e_fol = d_in[2];
  const void* e_buy = d_in[3];
  const void* e_bb  = d_in[4];
  const float* W_fol = (const float*)d_in[5];
  const float* W_buy = (const float*)d_in[6];
  const float* W_bb  = (const float*)d_in[7];
  const float* W_lu  = (const float*)d_in[8];
  const float* b_lu  = (const float*)d_in[9];
  const float* W_li  = (const float*)d_in[10];
  const float* b_li  = (const float*)d_in[11];
  float* out = (float*)d_out;

  // ws: bf16 arrays (64.16 MB) then ints (~8 MB). part region (19.3 MB)
  // ALIASES aggF+aggBB: part is dead before agg_all writes them (stream order).
  unsigned short* wsu = (unsigned short*)d_ws;
  unsigned short* aggF  = wsu;
  unsigned short* aggBB = wsu + 6400000;
  unsigned short* aggB  = wsu + 12800000;
  unsigned short* xu_b  = wsu + 19200000;
  unsigned short* xi_b  = wsu + 25600000;
  unsigned short* wfrag = wsu + 32000000;      // 81920 ushorts
  unsigned* part = (unsigned*)d_ws;            // KPART*NBUKT*SEGCAP = 4,816,896 uints
  int* ip = (int*)d_ws + 16040960;
  int* csr0 = ip;
  int* csr1 = ip + 600000;
  int* csr2 = ip + 1200000;
  int* rp0  = ip + 1800000;     // 50016 each
  int* rp1  = rp0 + 50016;
  int* rp2  = rp1 + 50016;
  int* counts = ip + 1950048;   // KPART*NBUKT = 37632
  int* bbase  = ip + 1987680;   // 588
  int* flag   = ip + 1988268;

  detect_i64<<<1, 64, 0, stream>>>((const unsigned int*)e_fol, flag);

  part_cvt<<<KPART + NB_CVT + NB_W, 256, 0, stream>>>(
      e_fol, e_bb, e_buy, part, counts, x_user, x_item,
      W_fol, W_bb, W_lu, W_buy, W_li, xu_b, xi_b, wfrag, flag);

  bucket_scan<<<1, 256, 0, stream>>>(counts, bbase, rp0, rp1, rp2);

  csr_build<<<3 * NBUK, 256, 0, stream>>>(part, counts, bbase,
                                          csr0, csr1, csr2, rp0, rp1, rp2);

  agg_all<<<3 * 12500, 256, 0, stream>>>(xu_b, xi_b, rp0, rp1, rp2,
                                         csr0, csr1, csr2, aggF, aggBB, aggB);

  mfma_gemm<<<2 * BLK_PER_HALF, 256, 0, stream>>>(
      aggF, aggBB, aggB, xu_b, xi_b, wfrag, b_lu, b_li, out);
}